// Round 13
// baseline (164.782 us; speedup 1.0000x reference)
//
#include <hip/hip_runtime.h>
#include <hip/hip_bf16.h>

// 3D multi-scale deformable attention, round 13 (= R12 + aligned-pair dup):
// - value pre-pass: fp32 (N,S,M,D) -> bf16 TRANSPOSED (N,M,S,D), stored TWICE:
//   copy E at ws+128 (base == 0 mod 128), copy O at ws+128+dataSize+64
//   (base == 64 mod 128). A pair [s,s+1] is 128B-aligned in copy E iff s even,
//   in copy O iff s odd -> phase 1 picks the copy by s&1; EVERY pair load is
//   exactly ONE cache line (was 1.5 avg) -> L2 txn traffic 4.3 -> 2.9 GB.
// - phase 1: 384 point-setups once -> LDS {4 pair-offsets, 4 wA, 4 wB}
// - phase 2: 4 pair loads/point, 16 B/lane, shfl_xor(4) reduce (R12 verbatim)
// - 3-tier fallback: dup (ws>=59.8MB) -> R12 single-copy -> fp32 (R3 kernel)
typedef float    f32x4 __attribute__((ext_vector_type(4)));
typedef unsigned u32x4 __attribute__((ext_vector_type(4)));

constexpr int kN  = 2;
constexpr int kS  = 29200;
constexpr int kM  = 8;
constexpr int kD  = 32;
constexpr int kL  = 3;
constexpr int kP  = 4;
constexpr int kLq = 29200;

constexpr int kGroups  = 32;                                // queries per block
constexpr int kQChunks = (kLq + kGroups - 1) / kGroups;     // 913
constexpr int kBlocks  = kN * kM * kQChunks;                // 14608 = 8 * 1826

constexpr size_t kData      = (size_t)kN * kS * kM * kD * 2;  // 29,900,800 B
constexpr size_t kCopyOff   = kData + 64;                     // copy O offset
constexpr size_t kWsNeedDup = 2 * kData + 320;                // 59,801,920 B
constexpr size_t kWsNeed1   = kData + 128;                    // R12 tier
constexpr int    kSliceB    = kS * kD * 2;                    // 1,868,800 B

// LDS: per point-slot 3 u32x4 (pair-offsets, wA, wB); group stride 37 vec
// (148 dw): 8 groups/wave start banks g*20 mod 32 = {0,20,8,28,16,4,24,12}
// -> disjoint bank-quads, conflict-free. (R12 verbatim)
constexpr int kSlotV = 3;
constexpr int kGrpV  = 12 * kSlotV + 1;                     // 37 vectors
constexpr int kLdsV  = kGroups * kGrpV;                     // 1184 (18,944 B)

__device__ __forceinline__ f32x4 ntload4(const float* p) {
  return __builtin_nontemporal_load(reinterpret_cast<const f32x4*>(p));
}

// ---- value fp32 (N,S,M,D) -> bf16 (N,M,S,D); 1 or 2 copies. ----
// outb = first-copy data base (site s at outb + s*64); copyOff = 0 or kCopyOff.
__global__ __launch_bounds__(256) void cvtT_kernel(
    const float* __restrict__ in, char* __restrict__ outb,
    unsigned long long copyOff)
{
  const int g     = blockIdx.x * 256 + threadIdx.x;  // < 1,868,800
  const int lane4 = g & 3;
  const int site  = g >> 2;              // (n*M + m)*S + s, s fastest
  const int s  = site % kS;
  const int nm = site / kS;
  const int m  = nm & 7;
  const int n  = nm >> 3;
  const float* ip = in + ((size_t)(n * kS + s) * kM + m) * kD + lane4 * 8;
  const f32x4 a = ntload4(ip);
  const f32x4 b = ntload4(ip + 4);
  unsigned short r[8];
  r[0] = __bfloat16_as_ushort(__float2bfloat16(a[0]));
  r[1] = __bfloat16_as_ushort(__float2bfloat16(a[1]));
  r[2] = __bfloat16_as_ushort(__float2bfloat16(a[2]));
  r[3] = __bfloat16_as_ushort(__float2bfloat16(a[3]));
  r[4] = __bfloat16_as_ushort(__float2bfloat16(b[0]));
  r[5] = __bfloat16_as_ushort(__float2bfloat16(b[1]));
  r[6] = __bfloat16_as_ushort(__float2bfloat16(b[2]));
  r[7] = __bfloat16_as_ushort(__float2bfloat16(b[3]));
  u32x4 pk;
  pk[0] = (unsigned)r[0] | ((unsigned)r[1] << 16);
  pk[1] = (unsigned)r[2] | ((unsigned)r[3] << 16);
  pk[2] = (unsigned)r[4] | ((unsigned)r[5] << 16);
  pk[3] = (unsigned)r[6] | ((unsigned)r[7] << 16);
  char* p0 = outb + (size_t)site * 64 + lane4 * 16;
  *reinterpret_cast<u32x4*>(p0) = pk;
  if (copyOff) *reinterpret_cast<u32x4*>(p0 + copyOff) = pk;
}

// ---------------- bf16 pair-fused main kernel ----------------
// DUP=1: db == ws+128 (0 mod 128); site s at db + s*64 (copy E) or
//        db + kCopyOff + s*64 (copy O, 64 mod 128); pick by s&1.
// DUP=0: db == ws; data at ws+64; offset = (s+1)*64 (R12 verbatim).
template <int DUP>
__global__ __launch_bounds__(256, 6) void msda3d_bf16_kernel(
    const char* __restrict__ db,
    const float* __restrict__ sloc,
    const float* __restrict__ attw,
    float* __restrict__ out)
{
  __shared__ u32x4 lds_v[kLdsV];

  // XCD-aware swizzle: XCD x handles combos {2x, 2x+1} sequentially.
  const int bid    = blockIdx.x;
  const int xcd    = bid & 7;
  const int li     = bid >> 3;
  const int half   = (li >= kQChunks) ? 1 : 0;
  const int combo  = xcd * 2 + half;            // 0..15 == n*8+m
  const int qblock = li - half * kQChunks;
  const int n = combo >> 3;
  const int m = combo & 7;
  const int tid = threadIdx.x;

  // ---------- phase 1: 384 point-setups, each computed once ----------
  for (int pidx = tid; pidx < 384; pidx += 256) {
    const int pt = pidx >> 5;                   // 0..11  (= l*4 + p)
    const int g  = pidx & 31;                   // query group 0..31
    const int l  = pt >> 2;                     // level 0..2
    const int T  = 16 >> l;
    const int H  = 40 >> l;
    const int W  = 40 >> l;
    const int base = (l == 0) ? 0 : ((l == 1) ? 25600 : 28800);

    int q = qblock * kGroups + g;
    if (q >= kLq) q = kLq - 1;                  // clamp (store is guarded)
    const size_t qm = (size_t)(n * kLq + q) * kM + m;
    const float gx = sloc[qm * 36 + pt * 3 + 0];
    const float gy = sloc[qm * 36 + pt * 3 + 1];
    const float gz = sloc[qm * 36 + pt * 3 + 2];
    const float aw = attw[qm * 12 + pt];

    const float x = gx * (float)W - 0.5f;
    const float y = gy * (float)H - 0.5f;
    const float z = gz * (float)T - 0.5f;
    const float xf = floorf(x), yf = floorf(y), zf = floorf(z);
    const float fx = x - xf, fy = y - yf, fz = z - zf;
    const int x0 = (int)xf, y0 = (int)yf, z0 = (int)zf;
    const int x1 = x0 + 1, y1 = y0 + 1, z1 = z0 + 1;
    const bool vx0 = (unsigned)x0 < (unsigned)W;
    const bool vx1 = (unsigned)x1 < (unsigned)W;
    const bool vy0 = (unsigned)y0 < (unsigned)H;
    const bool vy1 = (unsigned)y1 < (unsigned)H;
    const bool vz0 = (unsigned)z0 < (unsigned)T;
    const bool vz1 = (unsigned)z1 < (unsigned)T;
    const int yc0 = vy0 ? y0 : 0, yc1 = vy1 ? y1 : 0;
    const int zc0 = vz0 ? z0 : 0, zc1 = vz1 ? z1 : 0;
    const int r00 = (zc0 * H + yc0) * W;
    const int r01 = (zc0 * H + yc1) * W;
    const int r10 = (zc1 * H + yc0) * W;
    const int r11 = (zc1 * H + yc1) * W;
    const float wx0 = (1.f - fx) * aw, wx1 = fx * aw;
    const float wy0 = 1.f - fy, wy1 = fy;
    const float wz0 = 1.f - fz, wz1 = fz;
    const float w00 = wz0 * wy0, w01 = wz0 * wy1;
    const float w10 = wz1 * wy0, w11 = wz1 * wy1;
    const bool o00 = vz0 && vy0, o01 = vz0 && vy1;
    const bool o10 = vz1 && vy0, o11 = vz1 && vy1;

    const int s0 = base + r00 + x0;             // pair-start sites (x UNclamped)
    const int s1 = base + r01 + x0;
    const int s2 = base + r10 + x0;
    const int s3 = base + r11 + x0;

    u32x4 offs, wA, wB;
    if (DUP) {
      // even site -> copy E (aligned); odd -> copy O (aligned). s=-1 is odd.
      offs[0] = (unsigned)((s0 & 1) ? (size_t)kCopyOff + s0 * 64 : s0 * 64);
      offs[1] = (unsigned)((s1 & 1) ? (size_t)kCopyOff + s1 * 64 : s1 * 64);
      offs[2] = (unsigned)((s2 & 1) ? (size_t)kCopyOff + s2 * 64 : s2 * 64);
      offs[3] = (unsigned)((s3 & 1) ? (size_t)kCopyOff + s3 * 64 : s3 * 64);
    } else {
      offs[0] = (unsigned)(s0 + 1) << 6;        // data at db+64 (front pad)
      offs[1] = (unsigned)(s1 + 1) << 6;
      offs[2] = (unsigned)(s2 + 1) << 6;
      offs[3] = (unsigned)(s3 + 1) << 6;
    }
    wA[0] = __float_as_uint((o00 && vx0) ? w00 * wx0 : 0.f);
    wA[1] = __float_as_uint((o01 && vx0) ? w01 * wx0 : 0.f);
    wA[2] = __float_as_uint((o10 && vx0) ? w10 * wx0 : 0.f);
    wA[3] = __float_as_uint((o11 && vx0) ? w11 * wx0 : 0.f);
    wB[0] = __float_as_uint((o00 && vx1) ? w00 * wx1 : 0.f);
    wB[1] = __float_as_uint((o01 && vx1) ? w01 * wx1 : 0.f);
    wB[2] = __float_as_uint((o10 && vx1) ? w10 * wx1 : 0.f);
    wB[3] = __float_as_uint((o11 && vx1) ? w11 * wx1 : 0.f);

    u32x4* slot = lds_v + g * kGrpV + pt * kSlotV;
    slot[0] = offs;
    slot[1] = wA;
    slot[2] = wB;
  }
  __syncthreads();

  // ------ phase 2: gather, 4 PAIR loads per point (16 B/lane) ------
  const int group = tid >> 3;                   // 0..31
  const int lane8 = tid & 7;                    // 0..7
  const int q = qblock * kGroups + group;

  const char* __restrict__ vbase = db + (size_t)combo * kSliceB;
  const unsigned loff = (unsigned)lane8 * 16u;
  const bool hiLane = (lane8 >= 4);
  const u32x4* slot0 = lds_v + group * kGrpV;

  f32x4 acc0 = {0.f, 0.f, 0.f, 0.f};
  f32x4 acc1 = {0.f, 0.f, 0.f, 0.f};

#pragma unroll 1
  for (int pt = 0; pt < 12; ++pt) {
    const u32x4 offs = slot0[pt * kSlotV + 0];
    const u32x4 wA   = slot0[pt * kSlotV + 1];
    const u32x4 wB   = slot0[pt * kSlotV + 2];

#pragma unroll
    for (int i = 0; i < 4; ++i) {
      const float w_ = __uint_as_float(hiLane ? wB[i] : wA[i]);
      const u32x4 v = *reinterpret_cast<const u32x4*>(vbase + offs[i] + loff);
      acc0[0] = fmaf(__uint_as_float(v[0] << 16),         w_, acc0[0]);
      acc0[1] = fmaf(__uint_as_float(v[0] & 0xffff0000u), w_, acc0[1]);
      acc0[2] = fmaf(__uint_as_float(v[1] << 16),         w_, acc0[2]);
      acc0[3] = fmaf(__uint_as_float(v[1] & 0xffff0000u), w_, acc0[3]);
      acc1[0] = fmaf(__uint_as_float(v[2] << 16),         w_, acc1[0]);
      acc1[1] = fmaf(__uint_as_float(v[2] & 0xffff0000u), w_, acc1[1]);
      acc1[2] = fmaf(__uint_as_float(v[3] << 16),         w_, acc1[2]);
      acc1[3] = fmaf(__uint_as_float(v[3] & 0xffff0000u), w_, acc1[3]);
    }
  }

  // Pairwise reduce lane L with lane L^4 (x0-part + x1-part of same channels)
  f32x4 s0v, s1v;
#pragma unroll
  for (int j = 0; j < 4; ++j) {
    s0v[j] = acc0[j] + __shfl_xor(acc0[j], 4);
    s1v[j] = acc1[j] + __shfl_xor(acc1[j], 4);
  }
  const f32x4 stv = hiLane ? s1v : s0v;

  if (q < kLq) {
    float* __restrict__ op = out + (size_t)(n * kLq + q) * (kM * kD) + m * kD +
                             (lane8 & 3) * 8 + (lane8 >> 2) * 4;
    __builtin_nontemporal_store(stv, reinterpret_cast<f32x4*>(op));
  }
}

// ---------------- fp32 fallback (round-3 kernel, verified) ----------------
__device__ __forceinline__ f32x4 load16f(const float* base, unsigned byteoff) {
  return *reinterpret_cast<const f32x4*>(
      reinterpret_cast<const char*>(base) + byteoff);
}

__global__ __launch_bounds__(256) void msda3d_f32_kernel(
    const float* __restrict__ value,
    const float* __restrict__ sloc,
    const float* __restrict__ attw,
    float* __restrict__ out)
{
  constexpr int LT[3]   = {16, 8, 4};
  constexpr int LH[3]   = {40, 20, 10};
  constexpr int LW[3]   = {40, 20, 10};
  constexpr int LOFF[3] = {0, 25600, 28800};

  const int bid    = blockIdx.x;
  const int xcd    = bid & 7;
  const int li     = bid >> 3;
  const int half   = (li >= kQChunks) ? 1 : 0;
  const int combo  = xcd * 2 + half;
  const int qblock = li - half * kQChunks;
  const int n = combo >> 3;
  const int m = combo & 7;

  const int group = threadIdx.x >> 3;
  const int lane8 = threadIdx.x & 7;
  const int q = qblock * kGroups + group;
  if (q >= kLq) return;

  const size_t qm = (size_t)(n * kLq + q) * kM + m;
  const float* __restrict__ lp = sloc + qm * (kL * kP * 3);
  const float* __restrict__ wp = attw + qm * (kL * kP);
  const float* __restrict__ vbase = value + ((size_t)n * kS * kM + m) * kD;
  const unsigned loff = (unsigned)lane8 * 16u;

  f32x4 acc = {0.f, 0.f, 0.f, 0.f};

#pragma unroll
  for (int l = 0; l < kL; ++l) {
    const int T = LT[l], H = LH[l], W = LW[l];
    const unsigned ubase = ((unsigned)LOFF[l] << 10) + loff;

    const f32x4 c0 = ntload4(lp + l * 12 + 0);
    const f32x4 c1 = ntload4(lp + l * 12 + 4);
    const f32x4 c2 = ntload4(lp + l * 12 + 8);
    const f32x4 w4 = ntload4(wp + l * 4);
    const float crd[12] = {c0[0], c0[1], c0[2], c0[3],
                           c1[0], c1[1], c1[2], c1[3],
                           c2[0], c2[1], c2[2], c2[3]};
    const float aww[4] = {w4[0], w4[1], w4[2], w4[3]};

#pragma unroll
    for (int p = 0; p < kP; ++p) {
      const float gx = crd[p * 3 + 0];
      const float gy = crd[p * 3 + 1];
      const float gz = crd[p * 3 + 2];
      const float aw = aww[p];
      const float x = gx * (float)W - 0.5f;
      const float y = gy * (float)H - 0.5f;
      const float z = gz * (float)T - 0.5f;
      const float xf = floorf(x), yf = floorf(y), zf = floorf(z);
      const float fx = x - xf, fy = y - yf, fz = z - zf;
      const int x0 = (int)xf, y0 = (int)yf, z0 = (int)zf;
      const int x1 = x0 + 1, y1 = y0 + 1, z1 = z0 + 1;
      const bool vx0 = (unsigned)x0 < (unsigned)W;
      const bool vx1 = (unsigned)x1 < (unsigned)W;
      const bool vy0 = (unsigned)y0 < (unsigned)H;
      const bool vy1 = (unsigned)y1 < (unsigned)H;
      const bool vz0 = (unsigned)z0 < (unsigned)T;
      const bool vz1 = (unsigned)z1 < (unsigned)T;
      const int xc0 = vx0 ? x0 : 0, xc1 = vx1 ? x1 : 0;
      const int yc0 = vy0 ? y0 : 0, yc1 = vy1 ? y1 : 0;
      const int zc0 = vz0 ? z0 : 0, zc1 = vz1 ? z1 : 0;
      const int r00 = (zc0 * H + yc0) * W;
      const int r01 = (zc0 * H + yc1) * W;
      const int r10 = (zc1 * H + yc0) * W;
      const int r11 = (zc1 * H + yc1) * W;
      const float wx0 = (1.f - fx) * aw, wx1 = fx * aw;
      const float wy0 = 1.f - fy, wy1 = fy;
      const float wz0 = 1.f - fz, wz1 = fz;
      const float w00 = wz0 * wy0, w01 = wz0 * wy1;
      const float w10 = wz1 * wy0, w11 = wz1 * wy1;
      const bool o00 = vz0 && vy0, o01 = vz0 && vy1;
      const bool o10 = vz1 && vy0, o11 = vz1 && vy1;

      unsigned off[8];
      float cw[8];
      off[0] = ubase + ((unsigned)(r00 + xc0) << 10);
      off[1] = ubase + ((unsigned)(r00 + xc1) << 10);
      off[2] = ubase + ((unsigned)(r01 + xc0) << 10);
      off[3] = ubase + ((unsigned)(r01 + xc1) << 10);
      off[4] = ubase + ((unsigned)(r10 + xc0) << 10);
      off[5] = ubase + ((unsigned)(r10 + xc1) << 10);
      off[6] = ubase + ((unsigned)(r11 + xc0) << 10);
      off[7] = ubase + ((unsigned)(r11 + xc1) << 10);
      cw[0] = (o00 && vx0) ? w00 * wx0 : 0.f;
      cw[1] = (o00 && vx1) ? w00 * wx1 : 0.f;
      cw[2] = (o01 && vx0) ? w01 * wx0 : 0.f;
      cw[3] = (o01 && vx1) ? w01 * wx1 : 0.f;
      cw[4] = (o10 && vx0) ? w10 * wx0 : 0.f;
      cw[5] = (o10 && vx1) ? w10 * wx1 : 0.f;
      cw[6] = (o11 && vx0) ? w11 * wx0 : 0.f;
      cw[7] = (o11 && vx1) ? w11 * wx1 : 0.f;

      f32x4 v[8];
#pragma unroll
      for (int c = 0; c < 8; ++c) v[c] = load16f(vbase, off[c]);
#pragma unroll
      for (int c = 0; c < 8; ++c) acc += v[c] * cw[c];
    }
  }

  float* __restrict__ op =
      out + (size_t)(n * kLq + q) * (kM * kD) + m * kD + lane8 * 4;
  __builtin_nontemporal_store(acc, reinterpret_cast<f32x4*>(op));
}

extern "C" void kernel_launch(void* const* d_in, const int* in_sizes, int n_in,
                              void* d_out, int out_size, void* d_ws, size_t ws_size,
                              hipStream_t stream) {
  const float* value = (const float*)d_in[0];
  // d_in[1] = value_spatial_shapes (int32) — static, hardcoded above.
  const float* sloc  = (const float*)d_in[2];
  const float* attw  = (const float*)d_in[3];
  float* out = (float*)d_out;

  const int nThreads = kN * kM * kS * 4;         // 4 lanes per site
  if (ws_size >= kWsNeedDup) {
    // dup tier: copy E data base at ws+128 (0 mod 128), copy O at +kCopyOff.
    char* e = (char*)d_ws + 128;
    cvtT_kernel<<<nThreads / 256, 256, 0, stream>>>(value, e, kCopyOff);
    msda3d_bf16_kernel<1><<<kBlocks, 256, 0, stream>>>(e, sloc, attw, out);
  } else if (ws_size >= kWsNeed1) {
    // R12 tier: single copy, data at ws+64, offsets pad-shifted (+1).
    char* e = (char*)d_ws + 64;
    cvtT_kernel<<<nThreads / 256, 256, 0, stream>>>(value, e, 0ull);
    msda3d_bf16_kernel<0><<<kBlocks, 256, 0, stream>>>(
        (const char*)d_ws, sloc, attw, out);
  } else {
    msda3d_f32_kernel<<<kBlocks, 256, 0, stream>>>(value, sloc, attw, out);
  }
}